// Round 9
// baseline (2936.556 us; speedup 1.0000x reference)
//
#include <hip/hip_runtime.h>

// PASSING numerics contract (round 5, absmax 0.00195): every conv output must
// be a strictly sequential fp32 FMA chain in (ky,kx outer, cin inner) order,
// bias added after, fp32 stores. MLP layers: per-output sequential ascending-i
// chain, +bias, lrelu. Do NOT reorder/split K, do NOT change dtype.
//
// Round 9: LDS-free conv. Round-8 conv stalled at VALUBusy 29% because the
// K-loop mixed ds_read (input) with s_load (weights): SMEM is out-of-order so
// the compiler emits s_waitcnt lgkmcnt(0) full drains -> ~150 cyc scalar
// latency exposed per cin. Now: inputs via per-lane global_load (vmcnt, deep
// pipeline), weights via s_load (sole lgkmcnt user -> 1-deep prefetch works).
// Wave = 16 m x (16x8 pixel tile, 2 px/lane): 64 FMA / 64B scalar per cin;
// ~3 waves/SIMD on big layers gives TLP cover. FMA chain order unchanged.

#define HW2 13456   // 116*116
#define NF  12
#define NGF 4

__device__ __forceinline__ float lrelu_f(float x) { return x > 0.f ? x : 0.01f * x; }

// ---------------- build x0: (4,16,116,116) = concat(gf bcast, features) ------------
__global__ __launch_bounds__(256) void k_buildx0(const float* __restrict__ features,
                                                 const float* __restrict__ gf,
                                                 float* __restrict__ out) {
    int i = blockIdx.x * 256 + threadIdx.x;
    const int total = 4 * 16 * HW2;
    if (i >= total) return;
    int n  = i / (16 * HW2);
    int r  = i - n * (16 * HW2);
    int c  = r / HW2;
    int yx = r - c * HW2;
    float v = (c < NGF) ? gf[c] : features[(n * NF + (c - NGF)) * HW2 + yx];
    out[i] = v;
}

// ---------------- weight transpose: W[m][cin][ky][kx] -> Wt[kyx][cin][m] -----------
__global__ __launch_bounds__(256) void k_wt(const float* __restrict__ w,
                                            float* __restrict__ wt,
                                            int Cout, int Cin) {
    int i = blockIdx.x * 256 + threadIdx.x;
    int total = Cout * Cin * 9;
    if (i >= total) return;
    int m   = i / (Cin * 9);
    int r   = i - m * (Cin * 9);
    int cin = r / 9;
    int kyx = r - cin * 9;
    wt[(kyx * Cin + cin) * Cout + m] = w[i];
}

// ---------------- small transpose for kp weights: (64,64) -> [k][o] ----------------
__global__ __launch_bounds__(256) void k_wt2(const float* __restrict__ w,
                                             float* __restrict__ wt) {
    int i = blockIdx.x * 256 + threadIdx.x;  // 4096
    if (i >= 4096) return;
    int o = i >> 6, k = i & 63;
    wt[k * 64 + o] = w[i];
}

// ---------------- direct 3x3 VALID conv, LDS-free, order-preserving ----------------
// Block: 256 threads = 4 waves. Wave: 16 m-channels (uniform s_load weights),
// lane = pixel column of a 16x8 tile (2 pixels: oy0 and oy0+8).
// blockIdx.z = n*(COUT/64) + mh; wave m-base = mh*64 + wave*16.
template <int CIN>
__global__ __launch_bounds__(256, 3) void k_convg(const float* __restrict__ in,
                                                  const float* __restrict__ wt,
                                                  const float* __restrict__ bias,
                                                  float* __restrict__ out,
                                                  int H, int W, int COUT,
                                                  int relu, int tout) {
    const int OH = H - 2, OW = W - 2;
    const int MB = COUT >> 6;
    const int z  = blockIdx.z;
    const int n  = z / MB;
    const int mh = z - n * MB;

    const int tid  = threadIdx.x, lane = tid & 63;
    const int wv   = __builtin_amdgcn_readfirstlane(tid >> 6);
    const int mbase = mh * 64 + wv * 16;
    const int ly = lane >> 3, lx = lane & 7;
    const int oy0 = blockIdx.y * 16 + ly;
    const int oy1 = oy0 + 8;
    const int ox  = blockIdx.x * 8 + lx;
    // clamped coords for loads (clamped values are never stored)
    const int cy0 = min(oy0, OH - 1), cy1 = min(oy1, OH - 1), cx = min(ox, OW - 1);

    const float* inb = in + (size_t)n * CIN * H * W;
    const int HW = H * W;

    float acc[16][2];
    #pragma unroll
    for (int mi = 0; mi < 16; ++mi) { acc[mi][0] = 0.f; acc[mi][1] = 0.f; }

    #pragma unroll
    for (int ky = 0; ky < 3; ++ky) {
        #pragma unroll
        for (int kx = 0; kx < 3; ++kx) {
            const float* ia = inb + (cy0 + ky) * W + (cx + kx);
            const float* ib = inb + (cy1 + ky) * W + (cx + kx);
            const float* wr = wt + (size_t)((ky * 3 + kx) * CIN) * COUT + mbase;
            for (int cin = 0; cin < CIN; ++cin) {
                float v0 = ia[cin * HW];            // global_load (vmcnt)
                float v1 = ib[cin * HW];
                const float* w = wr + cin * COUT;   // uniform -> s_load_dwordx16
                #pragma unroll
                for (int mi = 0; mi < 16; ++mi) {
                    acc[mi][0] += w[mi] * v0;
                    acc[mi][1] += w[mi] * v1;
                }
            }
        }
    }

    if (ox < OW) {
        #pragma unroll
        for (int p = 0; p < 2; ++p) {
            int oy = p ? oy1 : oy0;
            if (oy >= OH) continue;
            if (tout) {
                float* ob = out + (size_t)(oy * OW + ox) * COUT;
                #pragma unroll
                for (int mi = 0; mi < 16; ++mi) {
                    int m = mbase + mi;
                    float val = acc[mi][p] + bias[m];
                    if (relu) val = lrelu_f(val);
                    ob[m] = val;
                }
            } else {
                #pragma unroll
                for (int mi = 0; mi < 16; ++mi) {
                    int m = mbase + mi;
                    float val = acc[mi][p] + bias[m];
                    if (relu) val = lrelu_f(val);
                    out[(((size_t)n * COUT + m) * OH + oy) * OW + ox] = val;
                }
            }
        }
    }
}

// ---------------- max over spp: (4,128,102,102) -> (128,102,102) ----------------
__global__ __launch_bounds__(256) void k_sppmax(const float* __restrict__ in,
                                                float* __restrict__ out) {
    int i = blockIdx.x * 256 + threadIdx.x;
    const int total = 128 * 102 * 102;  // 1331712
    if (i >= total) return;
    float m = in[i];
    #pragma unroll
    for (int s = 1; s < 4; ++s) m = fmaxf(m, in[i + s * total]);
    out[i] = m;
}

// ---------------- fused per-tap MLP -> wts (921600), tile-GEMM layers ----------
__global__ __launch_bounds__(256) void k_mlp(const float* __restrict__ features,
                                             const float* __restrict__ pfeat_t,  // (9216,64)
                                             const float* __restrict__ sf_w,     // (64,12)
                                             const float* __restrict__ sf_b,
                                             const float* __restrict__ w0t,      // [k][o]
                                             const float* __restrict__ b0,
                                             const float* __restrict__ w1t,      // [k][o]
                                             const float* __restrict__ b1,
                                             const float* __restrict__ w2, const float* __restrict__ b2,
                                             float* __restrict__ wts) {
    __shared__ float vx[64][256];  // [k][tap]  64 KB
    const int t   = threadIdx.x;
    const int gid = blockIdx.x * 256 + t;  // 3600*256 = 921600 exactly
    {
        int p  = gid / 100;
        int r  = gid - p * 100;
        int s  = r / 25;
        int tp = r - s * 25;
        int dy = tp / 5;
        int dx = tp - dy * 5;
        int h  = p / 96;
        int w  = p - h * 96;

        int y = 8 + h + dy, x = 8 + w + dx;
        const float* fb = features + (size_t)(s * NF) * HW2 + (size_t)y * 116 + x;
        float f[12];
        #pragma unroll
        for (int i = 0; i < 12; ++i) f[i] = fb[i * HW2];
        f[0] += (float)(dx - 2);
        f[1] += (float)(dy - 2);

        const float* pft = pfeat_t + (size_t)p * 64;
        #pragma unroll
        for (int o = 0; o < 64; ++o) {
            float a = 0.f;
            #pragma unroll
            for (int i = 0; i < 12; ++i) a += sf_w[o * 12 + i] * f[i];
            a += sf_b[o];
            vx[o][t] = pft[o] + a;
        }
    }
    __syncthreads();

    const int lane = t & 63;
    const int og   = 16 * __builtin_amdgcn_readfirstlane(t >> 6);
    const int tl   = lane * 4;

    // ---- kp0 ----
    {
        float acc[16][4];
        #pragma unroll
        for (int j = 0; j < 16; ++j)
            #pragma unroll
            for (int c = 0; c < 4; ++c) acc[j][c] = 0.f;
        #pragma unroll 4
        for (int k = 0; k < 64; ++k) {
            float4 xv = *(const float4*)(&vx[k][tl]);
            const float* wr = w0t + k * 64 + og;
            #pragma unroll
            for (int j = 0; j < 16; ++j) {
                float wj = wr[j];
                acc[j][0] += wj * xv.x; acc[j][1] += wj * xv.y;
                acc[j][2] += wj * xv.z; acc[j][3] += wj * xv.w;
            }
        }
        __syncthreads();
        #pragma unroll
        for (int j = 0; j < 16; ++j) {
            float bj = b0[og + j];
            float4 ov;
            ov.x = lrelu_f(acc[j][0] + bj); ov.y = lrelu_f(acc[j][1] + bj);
            ov.z = lrelu_f(acc[j][2] + bj); ov.w = lrelu_f(acc[j][3] + bj);
            *(float4*)(&vx[og + j][tl]) = ov;
        }
        __syncthreads();
    }

    // ---- kp1 ----
    {
        float acc[16][4];
        #pragma unroll
        for (int j = 0; j < 16; ++j)
            #pragma unroll
            for (int c = 0; c < 4; ++c) acc[j][c] = 0.f;
        #pragma unroll 4
        for (int k = 0; k < 64; ++k) {
            float4 xv = *(const float4*)(&vx[k][tl]);
            const float* wr = w1t + k * 64 + og;
            #pragma unroll
            for (int j = 0; j < 16; ++j) {
                float wj = wr[j];
                acc[j][0] += wj * xv.x; acc[j][1] += wj * xv.y;
                acc[j][2] += wj * xv.z; acc[j][3] += wj * xv.w;
            }
        }
        __syncthreads();
        #pragma unroll
        for (int j = 0; j < 16; ++j) {
            float bj = b1[og + j];
            float4 ov;
            ov.x = lrelu_f(acc[j][0] + bj); ov.y = lrelu_f(acc[j][1] + bj);
            ov.z = lrelu_f(acc[j][2] + bj); ov.w = lrelu_f(acc[j][3] + bj);
            *(float4*)(&vx[og + j][tl]) = ov;
        }
        __syncthreads();
    }

    // ---- kp2 ----
    {
        float a = 0.f;
        #pragma unroll
        for (int i = 0; i < 64; ++i) a += w2[i] * vx[i][t];
        a += b2[0];
        wts[gid] = a;
    }
}

// ---------------- final weighted-radiance reduction -> out (3,96,96), fp32 --------
__global__ __launch_bounds__(256) void k_reduce(const float* __restrict__ wts,
                                                const float* __restrict__ radiance,
                                                float* __restrict__ out) {
    int p = blockIdx.x * 256 + threadIdx.x;  // 9216
    if (p >= 9216) return;
    int h = p / 96, w = p - h * 96;
    float sw = 0.f, un0 = 0.f, un1 = 0.f, un2 = 0.f;
    const float* wp = wts + (size_t)p * 100;
    for (int s = 0; s < 4; ++s) {
        #pragma unroll
        for (int dy = 0; dy < 5; ++dy) {
            #pragma unroll
            for (int dx = 0; dx < 5; ++dx) {
                float wv = wp[s * 25 + dy * 5 + dx];
                sw += wv;
                int y = 8 + h + dy, x = 8 + w + dx;
                const float* rb = radiance + (size_t)(s * 3) * HW2 + (size_t)y * 116 + x;
                un0 += wv * rb[0 * HW2];
                un1 += wv * rb[1 * HW2];
                un2 += wv * rb[2 * HW2];
            }
        }
    }
    float inv = 1.f / (sw + 1e-8f);
    out[0 * 9216 + p] = un0 * inv;
    out[1 * 9216 + p] = un1 * inv;
    out[2 * 9216 + p] = un2 * inv;
}

extern "C" void kernel_launch(void* const* d_in, const int* in_sizes, int n_in,
                              void* d_out, int out_size, void* d_ws, size_t ws_size,
                              hipStream_t stream) {
    const float* features = (const float*)d_in[0];
    const float* radiance = (const float*)d_in[1];
    const float* gf       = (const float*)d_in[2];
    const float* emb_w0   = (const float*)d_in[3];
    const float* emb_b0   = (const float*)d_in[4];
    const float* emb_w    = (const float*)d_in[5];
    const float* emb_b    = (const float*)d_in[6];
    const float* pf_w0    = (const float*)d_in[7];
    const float* pf_b0    = (const float*)d_in[8];
    const float* pf_w1    = (const float*)d_in[9];
    const float* pf_b1    = (const float*)d_in[10];
    const float* pf_w2    = (const float*)d_in[11];
    const float* pf_b2    = (const float*)d_in[12];
    const float* sf_w     = (const float*)d_in[13];
    const float* sf_b     = (const float*)d_in[14];
    const float* kp_w0    = (const float*)d_in[15];
    const float* kp_b0    = (const float*)d_in[16];
    const float* kp_w1    = (const float*)d_in[17];
    const float* kp_b1    = (const float*)d_in[18];
    const float* kp_w2    = (const float*)d_in[19];
    const float* kp_b2    = (const float*)d_in[20];
    float* out = (float*)d_out;

    // ---- workspace layout ----
    float* WT = (float*)d_ws;
    float* wt0  = WT;                      // conv1: 16x9x128      = 18432
    float* wtE0 = WT + 18432;              // emb i: 128x9x128     = 147456 each
    float* wtP0 = WT + 18432 + 6 * 147456; // 903168
    float* wtP1 = WT + 1050624;
    float* wtP2 = WT + 1198080;            // 64-out: 128x9x64 = 73728 (end 1271808)
    float* w0t  = WT + 1271808;            // kp0 transposed [k][o] = 4096
    float* w1t  = WT + 1275904;            // kp1 transposed        = 4096 (end 1280000)
    float* A = WT + 1280000;               // ping-pong fp32 buffers, 6653952 floats each
    float* B = A + 6653952;

    auto wtr = [&](const float* w, float* dst, int Cout, int Cin) {
        int total = Cout * Cin * 9;
        k_wt<<<dim3((total + 255) / 256), 256, 0, stream>>>(w, dst, Cout, Cin);
    };
    wtr(emb_w0, wt0, 128, 16);
    for (int i = 0; i < 6; ++i) wtr(emb_w + i * 147456, wtE0 + i * 147456, 128, 128);
    wtr(pf_w0, wtP0, 128, 128);
    wtr(pf_w1, wtP1, 128, 128);
    wtr(pf_w2, wtP2, 64, 128);
    k_wt2<<<dim3(16), 256, 0, stream>>>(kp_w0, w0t);
    k_wt2<<<dim3(16), 256, 0, stream>>>(kp_w1, w1t);

    k_buildx0<<<dim3((4 * 16 * HW2 + 255) / 256), 256, 0, stream>>>(features, gf, A);

    auto gridc = [](int H, int W, int N, int COUT) {
        int OH = H - 2, OW = W - 2;
        return dim3((OW + 7) / 8, (OH + 15) / 16, N * (COUT >> 6));
    };

    // embedding ladder
    k_convg<16><<<gridc(116, 116, 4, 128), 256, 0, stream>>>(A, wt0, emb_b0, B, 116, 116, 128, 1, 0);
    k_convg<128><<<gridc(114, 114, 4, 128), 256, 0, stream>>>(B, wtE0 + 0*147456, emb_b + 0*128, A, 114, 114, 128, 1, 0);
    k_convg<128><<<gridc(112, 112, 4, 128), 256, 0, stream>>>(A, wtE0 + 1*147456, emb_b + 1*128, B, 112, 112, 128, 1, 0);
    k_convg<128><<<gridc(110, 110, 4, 128), 256, 0, stream>>>(B, wtE0 + 2*147456, emb_b + 2*128, A, 110, 110, 128, 1, 0);
    k_convg<128><<<gridc(108, 108, 4, 128), 256, 0, stream>>>(A, wtE0 + 3*147456, emb_b + 3*128, B, 108, 108, 128, 1, 0);
    k_convg<128><<<gridc(106, 106, 4, 128), 256, 0, stream>>>(B, wtE0 + 4*147456, emb_b + 4*128, A, 106, 106, 128, 1, 0);
    k_convg<128><<<gridc(104, 104, 4, 128), 256, 0, stream>>>(A, wtE0 + 5*147456, emb_b + 5*128, B, 104, 104, 128, 0, 0);

    // max over spp: B (4,128,102,102) -> A (128,102,102)
    k_sppmax<<<dim3(1331712 / 256), 256, 0, stream>>>(B, A);

    // pixel-feature convs (N=1); last one stores transposed (9216,64)
    k_convg<128><<<gridc(102, 102, 1, 128), 256, 0, stream>>>(A, wtP0, pf_b0, B, 102, 102, 128, 1, 0);
    k_convg<128><<<gridc(100, 100, 1, 128), 256, 0, stream>>>(B, wtP1, pf_b1, A, 100, 100, 128, 1, 0);
    k_convg<128><<<gridc(98,  98,  1, 64),  256, 0, stream>>>(A, wtP2, pf_b2, B, 98,  98,  64,  0, 1);

    // fused MLP: pfeat_t in B -> wts in A (921600 floats)
    k_mlp<<<dim3(3600), 256, 0, stream>>>(features, B, sf_w, sf_b,
                                          w0t, kp_b0, w1t, kp_b1, kp_w2, kp_b2, A);

    // weighted radiance -> out
    k_reduce<<<dim3(36), 256, 0, stream>>>(A, radiance, out);
}

// Round 10
// 2329.218 us; speedup vs baseline: 1.2607x; 1.2607x over previous
//
#include <hip/hip_runtime.h>

// PASSING numerics contract (round 5, absmax 0.00195): every conv output must
// be a strictly sequential fp32 FMA chain in (ky,kx outer, cin inner) order,
// bias added after, fp32 stores. MLP layers: per-output sequential ascending-i
// chain, +bias, lrelu. Do NOT reorder/split K, do NOT change dtype.
//
// Round 10: traffic-fixed conv. Round 9 was fabric-bound (468 MB/dispatch;
// 301 MB writes vs 26.6 unique — partial-line cross-XCD RMW thrash). Now:
// wave tile = 32x * 2y (lane=pixel) -> every store instr = two FULL 128B
// lines written once; 512-thr block = 8 waves = all 128 Cout (no m-split,
// input fetched once); inputs per-lane global_load (vmcnt), weights uniform
// s_load_dwordx16 (sole lgkmcnt user). FMA chain order unchanged.

#define HW2 13456   // 116*116
#define NF  12
#define NGF 4

__device__ __forceinline__ float lrelu_f(float x) { return x > 0.f ? x : 0.01f * x; }

// ---------------- build x0: (4,16,116,116) = concat(gf bcast, features) ------------
__global__ __launch_bounds__(256) void k_buildx0(const float* __restrict__ features,
                                                 const float* __restrict__ gf,
                                                 float* __restrict__ out) {
    int i = blockIdx.x * 256 + threadIdx.x;
    const int total = 4 * 16 * HW2;
    if (i >= total) return;
    int n  = i / (16 * HW2);
    int r  = i - n * (16 * HW2);
    int c  = r / HW2;
    int yx = r - c * HW2;
    float v = (c < NGF) ? gf[c] : features[(n * NF + (c - NGF)) * HW2 + yx];
    out[i] = v;
}

// ---------------- weight transpose: W[m][cin][ky][kx] -> Wt[kyx][cin][m] -----------
__global__ __launch_bounds__(256) void k_wt(const float* __restrict__ w,
                                            float* __restrict__ wt,
                                            int Cout, int Cin) {
    int i = blockIdx.x * 256 + threadIdx.x;
    int total = Cout * Cin * 9;
    if (i >= total) return;
    int m   = i / (Cin * 9);
    int r   = i - m * (Cin * 9);
    int cin = r / 9;
    int kyx = r - cin * 9;
    wt[(kyx * Cin + cin) * Cout + m] = w[i];
}

// ---------------- small transpose for kp weights: (64,64) -> [k][o] ----------------
__global__ __launch_bounds__(256) void k_wt2(const float* __restrict__ w,
                                             float* __restrict__ wt) {
    int i = blockIdx.x * 256 + threadIdx.x;  // 4096
    if (i >= 4096) return;
    int o = i >> 6, k = i & 63;
    wt[k * 64 + o] = w[i];
}

// ---------------- direct 3x3 VALID conv, full-line writes, order-preserving --------
// Block: 512 threads = 8 waves. Wave w: m-slice [w*MW, (w+1)*MW), MW=COUT/8.
// Lane = pixel: lx = lane&31 (32 x), lyh = lane>>5 (2 y rows). Stores per mi:
// 64 lanes = two complete 128B lines. Inputs: per-lane global_load (vmcnt,
// coalesced 128B/row). Weights: wave-uniform s_load of wt[kyx][cin][mslice].
template <int CIN, int COUT>
__global__ __launch_bounds__(512) void k_convw(const float* __restrict__ in,
                                               const float* __restrict__ wt,
                                               const float* __restrict__ bias,
                                               float* __restrict__ out,
                                               int H, int W, int relu, int tout) {
    constexpr int MW = COUT / 8;
    const int OH = H - 2, OW = W - 2;
    const int n   = blockIdx.z;
    const int tid = threadIdx.x, lane = tid & 63;
    const int wv  = __builtin_amdgcn_readfirstlane(tid >> 6);  // 0..7
    const int mbase = wv * MW;
    const int lx = lane & 31, lyh = lane >> 5;
    const int oy = blockIdx.y * 2 + lyh;          // OH is even for all layers
    const int ox = blockIdx.x * 32 + lx;
    const int cx = min(ox, OW - 1);               // clamp for tail-tile loads

    const float* inb = in + (size_t)n * CIN * H * W;
    const int HW = H * W;

    float acc[MW];
    #pragma unroll
    for (int mi = 0; mi < MW; ++mi) acc[mi] = 0.f;

    // ---- K loop: ky,kx outer, cin inner (REQUIRED order) ----
    #pragma unroll
    for (int ky = 0; ky < 3; ++ky) {
        #pragma unroll
        for (int kx = 0; kx < 3; ++kx) {
            const float* ia = inb + (oy + ky) * W + (cx + kx);
            const float* wr = wt + (size_t)((ky * 3 + kx) * CIN) * COUT + mbase;
            #pragma unroll 2
            for (int cin = 0; cin < CIN; ++cin) {
                float v = ia[cin * HW];             // vector load (vmcnt)
                const float* w = wr + cin * COUT;   // uniform -> s_load_dwordx16
                #pragma unroll
                for (int mi = 0; mi < MW; ++mi)
                    acc[mi] += w[mi] * v;
            }
        }
    }

    if (ox < OW) {
        if (tout) {
            float* ob = out + (size_t)(oy * OW + ox) * COUT;
            #pragma unroll
            for (int mi = 0; mi < MW; ++mi) {
                int m = mbase + mi;
                float val = acc[mi] + bias[m];
                if (relu) val = lrelu_f(val);
                ob[m] = val;
            }
        } else {
            #pragma unroll
            for (int mi = 0; mi < MW; ++mi) {
                int m = mbase + mi;
                float val = acc[mi] + bias[m];
                if (relu) val = lrelu_f(val);
                out[(((size_t)n * COUT + m) * OH + oy) * OW + ox] = val;
            }
        }
    }
}

// ---------------- max over spp: (4,128,102,102) -> (128,102,102) ----------------
__global__ __launch_bounds__(256) void k_sppmax(const float* __restrict__ in,
                                                float* __restrict__ out) {
    int i = blockIdx.x * 256 + threadIdx.x;
    const int total = 128 * 102 * 102;  // 1331712
    if (i >= total) return;
    float m = in[i];
    #pragma unroll
    for (int s = 1; s < 4; ++s) m = fmaxf(m, in[i + s * total]);
    out[i] = m;
}

// ---------------- fused per-tap MLP -> wts (921600), tile-GEMM layers ----------
__global__ __launch_bounds__(256) void k_mlp(const float* __restrict__ features,
                                             const float* __restrict__ pfeat_t,  // (9216,64)
                                             const float* __restrict__ sf_w,     // (64,12)
                                             const float* __restrict__ sf_b,
                                             const float* __restrict__ w0t,      // [k][o]
                                             const float* __restrict__ b0,
                                             const float* __restrict__ w1t,      // [k][o]
                                             const float* __restrict__ b1,
                                             const float* __restrict__ w2, const float* __restrict__ b2,
                                             float* __restrict__ wts) {
    __shared__ float vx[64][256];  // [k][tap]  64 KB
    const int t   = threadIdx.x;
    const int gid = blockIdx.x * 256 + t;  // 3600*256 = 921600 exactly
    {
        int p  = gid / 100;
        int r  = gid - p * 100;
        int s  = r / 25;
        int tp = r - s * 25;
        int dy = tp / 5;
        int dx = tp - dy * 5;
        int h  = p / 96;
        int w  = p - h * 96;

        int y = 8 + h + dy, x = 8 + w + dx;
        const float* fb = features + (size_t)(s * NF) * HW2 + (size_t)y * 116 + x;
        float f[12];
        #pragma unroll
        for (int i = 0; i < 12; ++i) f[i] = fb[i * HW2];
        f[0] += (float)(dx - 2);
        f[1] += (float)(dy - 2);

        const float* pft = pfeat_t + (size_t)p * 64;
        #pragma unroll
        for (int o = 0; o < 64; ++o) {
            float a = 0.f;
            #pragma unroll
            for (int i = 0; i < 12; ++i) a += sf_w[o * 12 + i] * f[i];
            a += sf_b[o];
            vx[o][t] = pft[o] + a;
        }
    }
    __syncthreads();

    const int lane = t & 63;
    const int og   = 16 * __builtin_amdgcn_readfirstlane(t >> 6);
    const int tl   = lane * 4;

    // ---- kp0 ----
    {
        float acc[16][4];
        #pragma unroll
        for (int j = 0; j < 16; ++j)
            #pragma unroll
            for (int c = 0; c < 4; ++c) acc[j][c] = 0.f;
        #pragma unroll 4
        for (int k = 0; k < 64; ++k) {
            float4 xv = *(const float4*)(&vx[k][tl]);
            const float* wr = w0t + k * 64 + og;
            #pragma unroll
            for (int j = 0; j < 16; ++j) {
                float wj = wr[j];
                acc[j][0] += wj * xv.x; acc[j][1] += wj * xv.y;
                acc[j][2] += wj * xv.z; acc[j][3] += wj * xv.w;
            }
        }
        __syncthreads();
        #pragma unroll
        for (int j = 0; j < 16; ++j) {
            float bj = b0[og + j];
            float4 ov;
            ov.x = lrelu_f(acc[j][0] + bj); ov.y = lrelu_f(acc[j][1] + bj);
            ov.z = lrelu_f(acc[j][2] + bj); ov.w = lrelu_f(acc[j][3] + bj);
            *(float4*)(&vx[og + j][tl]) = ov;
        }
        __syncthreads();
    }

    // ---- kp1 ----
    {
        float acc[16][4];
        #pragma unroll
        for (int j = 0; j < 16; ++j)
            #pragma unroll
            for (int c = 0; c < 4; ++c) acc[j][c] = 0.f;
        #pragma unroll 4
        for (int k = 0; k < 64; ++k) {
            float4 xv = *(const float4*)(&vx[k][tl]);
            const float* wr = w1t + k * 64 + og;
            #pragma unroll
            for (int j = 0; j < 16; ++j) {
                float wj = wr[j];
                acc[j][0] += wj * xv.x; acc[j][1] += wj * xv.y;
                acc[j][2] += wj * xv.z; acc[j][3] += wj * xv.w;
            }
        }
        __syncthreads();
        #pragma unroll
        for (int j = 0; j < 16; ++j) {
            float bj = b1[og + j];
            float4 ov;
            ov.x = lrelu_f(acc[j][0] + bj); ov.y = lrelu_f(acc[j][1] + bj);
            ov.z = lrelu_f(acc[j][2] + bj); ov.w = lrelu_f(acc[j][3] + bj);
            *(float4*)(&vx[og + j][tl]) = ov;
        }
        __syncthreads();
    }

    // ---- kp2 ----
    {
        float a = 0.f;
        #pragma unroll
        for (int i = 0; i < 64; ++i) a += w2[i] * vx[i][t];
        a += b2[0];
        wts[gid] = a;
    }
}

// ---------------- final weighted-radiance reduction -> out (3,96,96), fp32 --------
__global__ __launch_bounds__(256) void k_reduce(const float* __restrict__ wts,
                                                const float* __restrict__ radiance,
                                                float* __restrict__ out) {
    int p = blockIdx.x * 256 + threadIdx.x;  // 9216
    if (p >= 9216) return;
    int h = p / 96, w = p - h * 96;
    float sw = 0.f, un0 = 0.f, un1 = 0.f, un2 = 0.f;
    const float* wp = wts + (size_t)p * 100;
    for (int s = 0; s < 4; ++s) {
        #pragma unroll
        for (int dy = 0; dy < 5; ++dy) {
            #pragma unroll
            for (int dx = 0; dx < 5; ++dx) {
                float wv = wp[s * 25 + dy * 5 + dx];
                sw += wv;
                int y = 8 + h + dy, x = 8 + w + dx;
                const float* rb = radiance + (size_t)(s * 3) * HW2 + (size_t)y * 116 + x;
                un0 += wv * rb[0 * HW2];
                un1 += wv * rb[1 * HW2];
                un2 += wv * rb[2 * HW2];
            }
        }
    }
    float inv = 1.f / (sw + 1e-8f);
    out[0 * 9216 + p] = un0 * inv;
    out[1 * 9216 + p] = un1 * inv;
    out[2 * 9216 + p] = un2 * inv;
}

extern "C" void kernel_launch(void* const* d_in, const int* in_sizes, int n_in,
                              void* d_out, int out_size, void* d_ws, size_t ws_size,
                              hipStream_t stream) {
    const float* features = (const float*)d_in[0];
    const float* radiance = (const float*)d_in[1];
    const float* gf       = (const float*)d_in[2];
    const float* emb_w0   = (const float*)d_in[3];
    const float* emb_b0   = (const float*)d_in[4];
    const float* emb_w    = (const float*)d_in[5];
    const float* emb_b    = (const float*)d_in[6];
    const float* pf_w0    = (const float*)d_in[7];
    const float* pf_b0    = (const float*)d_in[8];
    const float* pf_w1    = (const float*)d_in[9];
    const float* pf_b1    = (const float*)d_in[10];
    const float* pf_w2    = (const float*)d_in[11];
    const float* pf_b2    = (const float*)d_in[12];
    const float* sf_w     = (const float*)d_in[13];
    const float* sf_b     = (const float*)d_in[14];
    const float* kp_w0    = (const float*)d_in[15];
    const float* kp_b0    = (const float*)d_in[16];
    const float* kp_w1    = (const float*)d_in[17];
    const float* kp_b1    = (const float*)d_in[18];
    const float* kp_w2    = (const float*)d_in[19];
    const float* kp_b2    = (const float*)d_in[20];
    float* out = (float*)d_out;

    // ---- workspace layout ----
    float* WT = (float*)d_ws;
    float* wt0  = WT;                      // conv1: 16x9x128      = 18432
    float* wtE0 = WT + 18432;              // emb i: 128x9x128     = 147456 each
    float* wtP0 = WT + 18432 + 6 * 147456; // 903168
    float* wtP1 = WT + 1050624;
    float* wtP2 = WT + 1198080;            // 64-out: 128x9x64 = 73728 (end 1271808)
    float* w0t  = WT + 1271808;            // kp0 transposed [k][o] = 4096
    float* w1t  = WT + 1275904;            // kp1 transposed        = 4096 (end 1280000)
    float* A = WT + 1280000;               // ping-pong fp32 buffers, 6653952 floats each
    float* B = A + 6653952;

    auto wtr = [&](const float* w, float* dst, int Cout, int Cin) {
        int total = Cout * Cin * 9;
        k_wt<<<dim3((total + 255) / 256), 256, 0, stream>>>(w, dst, Cout, Cin);
    };
    wtr(emb_w0, wt0, 128, 16);
    for (int i = 0; i < 6; ++i) wtr(emb_w + i * 147456, wtE0 + i * 147456, 128, 128);
    wtr(pf_w0, wtP0, 128, 128);
    wtr(pf_w1, wtP1, 128, 128);
    wtr(pf_w2, wtP2, 64, 128);
    k_wt2<<<dim3(16), 256, 0, stream>>>(kp_w0, w0t);
    k_wt2<<<dim3(16), 256, 0, stream>>>(kp_w1, w1t);

    k_buildx0<<<dim3((4 * 16 * HW2 + 255) / 256), 256, 0, stream>>>(features, gf, A);

    auto gridc = [](int H, int W, int N) {
        int OH = H - 2, OW = W - 2;   // OH even for all layers
        return dim3((OW + 31) / 32, OH / 2, N);
    };

    // embedding ladder
    k_convw<16, 128><<<gridc(116, 116, 4), 512, 0, stream>>>(A, wt0, emb_b0, B, 116, 116, 1, 0);
    k_convw<128,128><<<gridc(114, 114, 4), 512, 0, stream>>>(B, wtE0 + 0*147456, emb_b + 0*128, A, 114, 114, 1, 0);
    k_convw<128,128><<<gridc(112, 112, 4), 512, 0, stream>>>(A, wtE0 + 1*147456, emb_b + 1*128, B, 112, 112, 1, 0);
    k_convw<128,128><<<gridc(110, 110, 4), 512, 0, stream>>>(B, wtE0 + 2*147456, emb_b + 2*128, A, 110, 110, 1, 0);
    k_convw<128,128><<<gridc(108, 108, 4), 512, 0, stream>>>(A, wtE0 + 3*147456, emb_b + 3*128, B, 108, 108, 1, 0);
    k_convw<128,128><<<gridc(106, 106, 4), 512, 0, stream>>>(B, wtE0 + 4*147456, emb_b + 4*128, A, 106, 106, 1, 0);
    k_convw<128,128><<<gridc(104, 104, 4), 512, 0, stream>>>(A, wtE0 + 5*147456, emb_b + 5*128, B, 104, 104, 0, 0);

    // max over spp: B (4,128,102,102) -> A (128,102,102)
    k_sppmax<<<dim3(1331712 / 256), 256, 0, stream>>>(B, A);

    // pixel-feature convs (N=1); last one stores transposed (9216,64)
    k_convw<128,128><<<gridc(102, 102, 1), 512, 0, stream>>>(A, wtP0, pf_b0, B, 102, 102, 1, 0);
    k_convw<128,128><<<gridc(100, 100, 1), 512, 0, stream>>>(B, wtP1, pf_b1, A, 100, 100, 1, 0);
    k_convw<128, 64><<<gridc(98,  98,  1), 512, 0, stream>>>(A, wtP2, pf_b2, B, 98,  98,  0, 1);

    // fused MLP: pfeat_t in B -> wts in A (921600 floats)
    k_mlp<<<dim3(3600), 256, 0, stream>>>(features, B, sf_w, sf_b,
                                          w0t, kp_b0, w1t, kp_b1, kp_w2, kp_b2, A);

    // weighted radiance -> out
    k_reduce<<<dim3(36), 256, 0, stream>>>(A, radiance, out);
}